// Round 10
// baseline (553.117 us; speedup 1.0000x reference)
//
#include <hip/hip_runtime.h>
#include <hip/hip_bf16.h>
#include <cstdint>
#include <type_traits>

#define N_NODES 100000
#define N_EDGES 500000
#define FEAT 128
#define HID 256
#define N_LINKS 16384

#define SCAN_CH 1024
#define SCAN_NB ((N_NODES + SCAN_CH - 1) / SCAN_CH)   // 98

typedef __attribute__((ext_vector_type(8))) short short8;     // 8 bf16 = 4 VGPRs
typedef __attribute__((ext_vector_type(4))) float floatx4;
typedef __attribute__((ext_vector_type(16))) float floatx16;  // 32x32 acc

// ---- scalar load/store ----
__device__ __forceinline__ float ldf(const float* p) { return *p; }
__device__ __forceinline__ float ldf(const __hip_bfloat16* p) { return __bfloat162float(*p); }
__device__ __forceinline__ void stf(float* p, float v) { *p = v; }
__device__ __forceinline__ void stf(__hip_bfloat16* p, float v) { *p = __float2bfloat16(v); }

// 4-wide bf16 load/store (8B)
__device__ __forceinline__ void load4(const __hip_bfloat16* p, float v[4]) {
    const uint2 q = *(const uint2*)p;
    v[0] = __uint_as_float(q.x << 16);
    v[1] = __uint_as_float(q.x & 0xffff0000u);
    v[2] = __uint_as_float(q.y << 16);
    v[3] = __uint_as_float(q.y & 0xffff0000u);
}
__device__ __forceinline__ void store4(__hip_bfloat16* p, const float v[4]) {
    __hip_bfloat16 b[4];
    b[0] = __float2bfloat16(v[0]); b[1] = __float2bfloat16(v[1]);
    b[2] = __float2bfloat16(v[2]); b[3] = __float2bfloat16(v[3]);
    *(uint2*)p = *(const uint2*)b;
}

// 8-wide bf16 load/store (16B)
__device__ __forceinline__ void load8(const __hip_bfloat16* p, float v[8]) {
    const uint4 q = *(const uint4*)p;
    v[0] = __uint_as_float(q.x << 16);
    v[1] = __uint_as_float(q.x & 0xffff0000u);
    v[2] = __uint_as_float(q.y << 16);
    v[3] = __uint_as_float(q.y & 0xffff0000u);
    v[4] = __uint_as_float(q.z << 16);
    v[5] = __uint_as_float(q.z & 0xffff0000u);
    v[6] = __uint_as_float(q.w << 16);
    v[7] = __uint_as_float(q.w & 0xffff0000u);
}
__device__ __forceinline__ void store8(__hip_bfloat16* p, const float v[8]) {
    __hip_bfloat16 b[8];
    #pragma unroll
    for (int i = 0; i < 8; i++) b[i] = __float2bfloat16(v[i]);
    *(uint4*)p = *(const uint4*)b;
}

// unpack a raw 16B bf16x8 chunk and accumulate into acc[8]
__device__ __forceinline__ void acc8(const uint4& q, float a[8]) {
    a[0] += __uint_as_float(q.x << 16);
    a[1] += __uint_as_float(q.x & 0xffff0000u);
    a[2] += __uint_as_float(q.y << 16);
    a[3] += __uint_as_float(q.y & 0xffff0000u);
    a[4] += __uint_as_float(q.z << 16);
    a[5] += __uint_as_float(q.z & 0xffff0000u);
    a[6] += __uint_as_float(q.w << 16);
    a[7] += __uint_as_float(q.w & 0xffff0000u);
}

// async global->LDS, 16B per lane; LDS dest = wave-uniform base + lane*16
__device__ __forceinline__ void gload_lds16(const short* g, short* lds) {
    __builtin_amdgcn_global_load_lds(
        reinterpret_cast<const __attribute__((address_space(1))) unsigned int*>(
            reinterpret_cast<uintptr_t>(g)),
        reinterpret_cast<__attribute__((address_space(3))) unsigned int*>(
            reinterpret_cast<uintptr_t>(lds)),
        16, 0, 0);
}

// defensive: any out-of-range index becomes 0 (wrong answer, not a fault)
__device__ __forceinline__ int clampi(int v, int n) { return ((unsigned)v < (unsigned)n) ? v : 0; }

// ---------------- utility ----------------

__global__ void zero_f32(float* p, int n) {
    int i = blockIdx.x * blockDim.x + threadIdx.x;
    if (i < n) p[i] = 0.0f;
}
__global__ void zero_i32(int* p, int n) {
    int i = blockIdx.x * blockDim.x + threadIdx.x;
    if (i < n) p[i] = 0;
}

// x (float4-wide) -> bf16
__global__ void cvt_x(const float4* __restrict__ x, __hip_bfloat16* __restrict__ xb, int n4) {
    int i = blockIdx.x * blockDim.x + threadIdx.x;
    if (i >= n4) return;
    float4 v = x[i];
    float a[4] = {v.x, v.y, v.z, v.w};
    store4(&xb[(size_t)i * 4], a);
}

// weights -> contiguous bf16 buffer, row-major (used by pred head p1 only now)
#define WOF_EMB 0
#define WOF_L0  32768
#define WOF_R0  98304
#define WOF_L1  163840
#define WOF_R1  229376
#define WOF_P1  294912
#define W_TOTAL 557056
__global__ void cvt_w(const float* __restrict__ w_emb, const float* __restrict__ wl0,
                      const float* __restrict__ wr0, const float* __restrict__ wl1,
                      const float* __restrict__ wr1, const float* __restrict__ wp1,
                      __hip_bfloat16* __restrict__ wb) {
    int i = blockIdx.x * blockDim.x + threadIdx.x;
    if (i >= W_TOTAL) return;
    float v;
    if      (i < WOF_L0) v = w_emb[i - WOF_EMB];
    else if (i < WOF_R0) v = wl0[i - WOF_L0];
    else if (i < WOF_L1) v = wr0[i - WOF_R0];
    else if (i < WOF_R1) v = wl1[i - WOF_L1];
    else if (i < WOF_P1) v = wr1[i - WOF_R1];
    else                 v = wp1[i - WOF_P1];
    wb[i] = __float2bfloat16(v);
}

// R13: packed "LDS image" layout for the gemm_kc staged B operand.
// Per matrix: [KS/8 ksegs][256 cols][8 bf16], element (kseg, n, j) = W[n][kseg*8+j].
#define POF_EMB 0
#define POF_L0  32768
#define POF_R0  98304
#define POF_L1  163840
#define POF_R1  229376
#define WP_TOTAL 294912
__global__ void cvt_w2(const float* __restrict__ w_emb, const float* __restrict__ wl0,
                       const float* __restrict__ wr0, const float* __restrict__ wl1,
                       const float* __restrict__ wr1, __hip_bfloat16* __restrict__ wbp) {
    int i = blockIdx.x * blockDim.x + threadIdx.x;
    if (i >= WP_TOTAL) return;
    const float* src; int off, ks;
    if      (i < POF_L0) { src = w_emb; off = POF_EMB; ks = 128; }
    else if (i < POF_R0) { src = wl0;   off = POF_L0;  ks = 256; }
    else if (i < POF_L1) { src = wr0;   off = POF_R0;  ks = 256; }
    else if (i < POF_R1) { src = wl1;   off = POF_L1;  ks = 256; }
    else                 { src = wr1;   off = POF_R1;  ks = 256; }
    int o = i - off;
    int kseg = o >> 11;        // / (256*8)
    int rem  = o & 2047;
    int n = rem >> 3, j = rem & 7;
    wbp[i] = __float2bfloat16(src[n * ks + kseg * 8 + j]);
}

// ---------------- CSR build ----------------

__global__ void count_deg(const int* __restrict__ dst, int* __restrict__ deg, int nE) {
    int e = blockIdx.x * blockDim.x + threadIdx.x;
    if (e < nE) atomicAdd(&deg[clampi(dst[e], N_NODES)], 1);
}

__global__ __launch_bounds__(256) void csr_block_sums(const int* __restrict__ deg, int* __restrict__ bsum) {
    __shared__ int red[256];
    int b = blockIdx.x, t = threadIdx.x;
    int s = 0;
    #pragma unroll
    for (int j = 0; j < 4; j++) {
        int i = b * SCAN_CH + t + j * 256;
        if (i < N_NODES) s += deg[i];
    }
    red[t] = s; __syncthreads();
    for (int o = 128; o > 0; o >>= 1) {
        if (t < o) red[t] += red[t + o];
        __syncthreads();
    }
    if (t == 0) bsum[b] = red[0];
}

__global__ __launch_bounds__(128) void csr_scan_partials(const int* __restrict__ bsum, int* __restrict__ bpre) {
    __shared__ int sc[128];
    int t = threadIdx.x;
    int v = (t < SCAN_NB) ? bsum[t] : 0;
    sc[t] = v; __syncthreads();
    for (int o = 1; o < 128; o <<= 1) {
        int x = (t >= o) ? sc[t - o] : 0;
        __syncthreads();
        sc[t] += x;
        __syncthreads();
    }
    if (t < SCAN_NB) bpre[t] = sc[t] - v;   // exclusive
}

__global__ __launch_bounds__(256) void csr_write_rowptr(const int* __restrict__ deg,
                                                        const int* __restrict__ bpre,
                                                        int* __restrict__ rowptr) {
    __shared__ int sc[256];
    int b = blockIdx.x, t = threadIdx.x;
    int base = bpre[b];
    int i0 = b * SCAN_CH + t * 4;
    int d[4];
    int s = 0;
    #pragma unroll
    for (int j = 0; j < 4; j++) {
        d[j] = (i0 + j < N_NODES) ? deg[i0 + j] : 0;
        s += d[j];
    }
    sc[t] = s; __syncthreads();
    for (int o = 1; o < 256; o <<= 1) {
        int x = (t >= o) ? sc[t - o] : 0;
        __syncthreads();
        sc[t] += x;
        __syncthreads();
    }
    int pre = base + sc[t] - s;
    #pragma unroll
    for (int j = 0; j < 4; j++) {
        if (i0 + j < N_NODES) rowptr[i0 + j] = pre;
        pre += d[j];
    }
}

__global__ void fill_buckets(const int* __restrict__ src, const int* __restrict__ dst,
                             int* __restrict__ rowptr, int* __restrict__ ebuf, int nE) {
    int e = blockIdx.x * blockDim.x + threadIdx.x;
    if (e >= nE) return;
    int d = clampi(dst[e], N_NODES);
    int pos = atomicAdd(&rowptr[d], 1);
    if (pos < nE) ebuf[pos] = clampi(src[e], N_NODES);
}

// DETERMINISM: fill_buckets slots edges in atomic arrival order (varies per run).
// Sorting each row makes summation order a pure function of the input multiset
// -> bit-exact output every call.
__global__ void sort_rows(const int* __restrict__ rowend, const int* __restrict__ deg,
                          int* __restrict__ ebuf) {
    int n = blockIdx.x * blockDim.x + threadIdx.x;
    if (n >= N_NODES) return;
    int end = rowend[n];
    int start = end - deg[n];
    for (int i = start + 1; i < end; i++) {          // insertion sort (mean deg ~5)
        int key = ebuf[i];
        int j = i - 1;
        while (j >= start && ebuf[j] > key) { ebuf[j + 1] = ebuf[j]; j--; }
        ebuf[j + 1] = key;
    }
}

// ---------------- gather aggregation ----------------
// R17: branch-free 8-deep batch; pad slots load the zero row at h[N_NODES]
// and are added unconditionally (+0.0, exact). Order fixed (self, then
// ascending-e slots incl. zero pads) -> bit-exact across runs.
// Grid: 12500 blocks x 8 nodes; half-per-node, 16B/lane.

__global__ __launch_bounds__(256) void gather_agg(const __hip_bfloat16* __restrict__ h,
                                                  const int* __restrict__ rowend,
                                                  const int* __restrict__ deg,
                                                  const int* __restrict__ ebuf,
                                                  __hip_bfloat16* __restrict__ agg) {
    int wave = threadIdx.x >> 6, lane = threadIdx.x & 63;
    int half = lane >> 5, l32 = lane & 31;
    int n = blockIdx.x * 8 + wave * 2 + half;       // 8 nodes per 256-thr block
    bool active = (n < N_NODES);
    int nn = active ? n : 0;
    int dg  = deg[nn];
    int end = rowend[nn];
    int start = end - dg;
    if (!active) { end = 0; start = 0; dg = 0; }

    float acc[8];
    {
        float sv[8];
        load8(&h[(long long)nn * HID + l32 * 8], sv);   // self row
        #pragma unroll
        for (int k = 0; k < 8; k++) acc[k] = sv[k];
    }

    for (int e = start; e < end; e += 8) {
        int cnt = end - e;                              // >= 1 inside loop
        uint4 raw[8];
        #pragma unroll
        for (int i = 0; i < 8; i++) {
            int t = e + i; t = (t < end) ? t : (end - 1);   // in-bounds ebuf idx
            int idx = ebuf[t];
            int s = (i < cnt) ? idx : N_NODES;              // pad -> zero row
            raw[i] = *(const uint4*)&h[(long long)s * HID + l32 * 8];
        }
        #pragma unroll
        for (int i = 0; i < 8; i++) acc8(raw[i], acc);      // pads add +0.0
    }

    float inv = 1.0f / (float)(dg + 1);
    #pragma unroll
    for (int k = 0; k < 8; k++) acc[k] *= inv;
    if (active) store8(&agg[(long long)n * HID + l32 * 8], acc);
}

// ============ R13/R21: K-concat LDS-staged GEMM, counted-vmcnt pipeline ============
// C = [A1|A2] @ [B1|B2]^T as ONE K=512 GEMM; 128 rows x 64 cols per block;
// grid = R17 walker (GX=128, cg=blockIdx.y slow — best measured locality:
// cg duplicates 128 apart in linear id -> same XCD L2, FETCH ~52 MB).
// R20 confirmed the XCD-L2 model but one-tile/block lost to the walker, so
// the remaining stall is the per-K-step __syncthreads: it drains vmcnt(0)
// INCLUDING the just-issued prefetch (m233's "2-phase stall").
// R21 (T4, counted vmcnt): 3 LDS buffers (72KB, still 2 blocks/CU),
// prefetch distance 2, raw s_barrier with s_waitcnt vmcnt(6) — stage(t+2)'s
// 6 loads/thread stay IN FLIGHT across the barrier; only stage(t+1) is
// awaited (vmcnt retires in issue order, m135). sched_barrier(0) after each
// barrier (rule #18). MFMA order per acc unchanged -> bit-exact.

template <int KS, bool DUAL, typename TC, bool RELU>
__global__ __launch_bounds__(256, 2) void gemm_kc(const __hip_bfloat16* __restrict__ A1,
                                                  const __hip_bfloat16* __restrict__ A2,
                                                  const __hip_bfloat16* __restrict__ Bp1,
                                                  const __hip_bfloat16* __restrict__ Bp2,
                                                  const float* __restrict__ bias,
                                                  TC* __restrict__ C, int M, int GX) {
    const int N = 256;
    const int NSTEP = (DUAL ? 2 : 1) * KS / 64;       // 64-wide K steps (2 or 16)
    __shared__ __align__(16) short As[3][128 * 64];   // 3 x 16 KB
    __shared__ __align__(16) short Bs[3][64 * 64];    // 3 x 8 KB   (72 KB total)

    const int tid = threadIdx.x;
    const int w = tid >> 6, lane = tid & 63;
    const int half = lane >> 5, l32 = lane & 31;
    const int cg = blockIdx.y;               // slow dim (R17 locality)

    const short* A1s = (const short*)A1;
    const short* A2s = (const short*)A2;
    const short* B1s = (const short*)Bp1;
    const short* B2s = (const short*)Bp2;

    const int NT = (M + 127) / 128;
    for (int tile = blockIdx.x; tile < NT; tile += GX) {
        const int row0 = tile * 128;

        // stage K-step t into buffer buf: 6 global_load_lds per thread
        // (A: 4, B: 2) — issue order fixed, vmcnt counts these in order.
        auto stage = [&](int buf, int t) {
            const short* Asrc; const short* Bsrc; int kl;
            if (!DUAL || t < KS / 64) { Asrc = A1s; Bsrc = B1s; kl = t * 64; }
            else                      { Asrc = A2s; Bsrc = B2s; kl = t * 64 - KS; }
            #pragma unroll
            for (int i = 0; i < 4; i++) {
                int idx = i * 256 + tid;             // 0..1023
                int row = idx >> 3, b16 = idx & 7;
                int gr = row0 + row; if (gr >= M) gr = M - 1;
                gload_lds16(Asrc + (size_t)gr * KS + kl + ((b16 ^ (row & 7)) * 8),
                            (short*)&As[buf][idx * 8]);
            }
            #pragma unroll
            for (int i = 0; i < 2; i++) {
                int idx = i * 256 + tid;             // 0..511
                int kseg = idx >> 6, col = idx & 63;
                gload_lds16(Bsrc + ((size_t)((kl >> 3) + kseg) * 256 + cg * 64 + col) * 8,
                            (short*)&Bs[buf][idx * 8]);
            }
        };

        floatx16 acc[2] = {};

        // prologue: stages 0 and 1 in flight; await stage 0 only
        stage(0, 0);
        stage(1, 1);
        asm volatile("s_waitcnt vmcnt(6)" ::: "memory");
        __builtin_amdgcn_s_barrier();
        __builtin_amdgcn_sched_barrier(0);

        for (int t = 0; t < NSTEP; t++) {
            const int cur = t % 3;
            if (t + 2 < NSTEP) stage((t + 2) % 3, t + 2);   // overwrites buffer
                                                            // read at t-1 (safe
                                                            // past its barrier)

            const int arow = w * 32 + l32;
            #pragma unroll
            for (int k16 = 0; k16 < 4; k16++) {
                int e = k16 * 2 + half;
                short8 a  = *(const short8*)&As[cur][(arow * 8 + (e ^ (l32 & 7))) * 8];
                short8 b0 = *(const short8*)&Bs[cur][(e * 64 + l32) * 8];
                short8 b1 = *(const short8*)&Bs[cur][(e * 64 + 32 + l32) * 8];
                acc[0] = __builtin_amdgcn_mfma_f32_32x32x16_bf16(a, b0, acc[0], 0, 0, 0);
                acc[1] = __builtin_amdgcn_mfma_f32_32x32x16_bf16(a, b1, acc[1], 0, 0, 0);
            }

            // await stage(t+1) (6 loads); stage(t+2)'s 6 stay in flight.
            if (t + 2 < NSTEP)
                asm volatile("s_waitcnt vmcnt(6)" ::: "memory");
            else
                asm volatile("s_waitcnt vmcnt(0)" ::: "memory");  // drain tail
            __builtin_amdgcn_s_barrier();
            __builtin_amdgcn_sched_barrier(0);
        }

        // epilogue: C/D col = lane&31, row = (reg&3) + 8*(reg>>2) + 4*half
        #pragma unroll
        for (int ct = 0; ct < 2; ct++) {
            int c = cg * 64 + ct * 32 + l32;
            float bc = bias[c];
            #pragma unroll
            for (int reg = 0; reg < 16; reg++) {
                int rr = row0 + w * 32 + (reg & 3) + 8 * (reg >> 2) + 4 * half;
                if (rr < M) {
                    float v = acc[ct][reg] + bc;
                    if (RELU) v = fmaxf(v, 0.0f);
                    stf(&C[(size_t)rr * N + c], v);
                }
            }
        }
    }
}

// ---------------- rolling-stage MFMA GEMM (K=1024 pred head, 16x16x32) ----------------

template <int RT, bool DUAL, typename TC, bool RELU>
__global__ __launch_bounds__(256, 2) void mfma_gemm(const __hip_bfloat16* __restrict__ A1,
                                                    const __hip_bfloat16* __restrict__ A2,
                                                    const __hip_bfloat16* __restrict__ B1,
                                                    const __hip_bfloat16* __restrict__ B2,
                                                    const float* __restrict__ bias,
                                                    TC* __restrict__ C, int M, int K) {
    const int N = 256;
    const int SZ = 4 * 256 * 8;
    __shared__ __align__(16) short Bs[DUAL ? 4 : 2][SZ];

    int w = threadIdx.x >> 6, lane = threadIdx.x & 63;
    int quad = lane >> 4, l16 = lane & 15;
    int wr = w >> 1, wc = w & 1;
    const int WROWS = RT * 16;
    int row0 = blockIdx.x * (2 * WROWS) + wr * WROWS;
    int colbase = wc * 128;

    const short* A1s = (const short*)A1;
    const short* A2s = (const short*)A2;
    const short* B1s = (const short*)B1;
    const short* B2s = (const short*)B2;

    floatx4 acc[RT][8] = {};

    int r[RT];
    #pragma unroll
    for (int i = 0; i < RT; i++) {
        int rr = row0 + i * 16 + l16;
        r[i] = rr < M ? rr : M - 1;
    }
    int scol = threadIdx.x;
    int ldsoff = (w * 64) * 8;

    short8 a1c[RT], a2c[RT], a1n[RT], a2n[RT];

    #pragma unroll
    for (int q = 0; q < 4; q++) {
        gload_lds16(B1s + (size_t)scol * K + q * 8, &Bs[0][q * 256 * 8 + ldsoff]);
        if (DUAL)
            gload_lds16(B2s + (size_t)scol * K + q * 8, &Bs[2][q * 256 * 8 + ldsoff]);
    }
    {
        int ka = quad * 8;
        #pragma unroll
        for (int i = 0; i < RT; i++) {
            a1c[i] = *(const short8*)(A1s + (size_t)r[i] * K + ka);
            if (DUAL) a2c[i] = *(const short8*)(A2s + (size_t)r[i] * K + ka);
        }
    }
    __syncthreads();

    const int NK = K / 32;
    int cur = 0;
    for (int k = 0; k < NK; k++) {
        if (k + 1 < NK) {
            int k0n = (k + 1) * 32;
            #pragma unroll
            for (int q = 0; q < 4; q++) {
                gload_lds16(B1s + (size_t)scol * K + k0n + q * 8,
                            &Bs[cur ^ 1][q * 256 * 8 + ldsoff]);
                if (DUAL)
                    gload_lds16(B2s + (size_t)scol * K + k0n + q * 8,
                                &Bs[2 + (cur ^ 1)][q * 256 * 8 + ldsoff]);
            }
            int ka = k0n + quad * 8;
            #pragma unroll
            for (int i = 0; i < RT; i++) {
                a1n[i] = *(const short8*)(A1s + (size_t)r[i] * K + ka);
                if (DUAL) a2n[i] = *(const short8*)(A2s + (size_t)r[i] * K + ka);
            }
        }

        short8 b1[8], b2[8];
        #pragma unroll
        for (int ct = 0; ct < 8; ct++) {
            int col = colbase + ct * 16 + l16;
            b1[ct] = *(const short8*)&Bs[cur][(quad * 256 + col) * 8];
            if (DUAL) b2[ct] = *(const short8*)&Bs[2 + cur][(quad * 256 + col) * 8];
        }
        #pragma unroll
        for (int i = 0; i < RT; i++) {
            #pragma unroll
            for (int ct = 0; ct < 8; ct++) {
                acc[i][ct] = __builtin_amdgcn_mfma_f32_16x16x32_bf16(a1c[i], b1[ct], acc[i][ct], 0, 0, 0);
                if (DUAL)
                    acc[i][ct] = __builtin_amdgcn_mfma_f32_16x16x32_bf16(a2c[i], b2[ct], acc[i][ct], 0, 0, 0);
            }
        }
        __syncthreads();
        cur ^= 1;
        #pragma unroll
        for (int i = 0; i < RT; i++) {
            a1c[i] = a1n[i];
            if (DUAL) a2c[i] = a2n[i];
        }
    }

    #pragma unroll
    for (int rt = 0; rt < RT; rt++) {
        #pragma unroll
        for (int ct = 0; ct < 8; ct++) {
            int c = colbase + ct * 16 + l16;
            float bc = bias[c];
            #pragma unroll
            for (int i = 0; i < 4; i++) {
                int rr = row0 + rt * 16 + quad * 4 + i;
                if (rr < M) {
                    float v = acc[rt][ct][i] + bc;
                    if (RELU) v = fmaxf(v, 0.0f);
                    stf(&C[(size_t)rr * N + c], v);
                }
            }
        }
    }
}

// ---------------- prediction head ----------------

__global__ __launch_bounds__(256) void build_comb(const __hip_bfloat16* __restrict__ h,
                                                  const int* __restrict__ src_idx,
                                                  const int* __restrict__ dst_idx,
                                                  __hip_bfloat16* __restrict__ comb) {
    int row = blockIdx.x;
    int t = threadIdx.x;
    int s = clampi(src_idx[row], N_NODES);
    int d = clampi(dst_idx[row], N_NODES);
    float sv = ldf(&h[(long long)s * HID + t]);
    float dv = ldf(&h[(long long)d * HID + t]);
    __hip_bfloat16* cr = &comb[(long long)row * (4 * HID)];
    stf(&cr[t], sv);
    stf(&cr[HID + t], dv);
    stf(&cr[2 * HID + t], sv * dv);
    stf(&cr[3 * HID + t], fabsf(sv - dv));
}

__global__ __launch_bounds__(256) void pred_final(const float* __restrict__ hidden,
                                                  const float* __restrict__ wp2,
                                                  const float* __restrict__ bp2,
                                                  float* __restrict__ out) {
    int wave = threadIdx.x >> 6;
    int lane = threadIdx.x & 63;
    int row = blockIdx.x * 4 + wave;
    if (row >= N_LINKS) return;
    const float4 hv = *(const float4*)&hidden[(long long)row * HID + lane * 4];
    const float4 wv = *(const float4*)&wp2[lane * 4];
    float v = hv.x * wv.x + hv.y * wv.y + hv.z * wv.z + hv.w * wv.w;
    #pragma unroll
    for (int off = 32; off > 0; off >>= 1) v += __shfl_down(v, off, 64);
    if (lane == 0) out[row] = 1.0f / (1.0f + expf(-(v + bp2[0])));
}

// ---------------- launch ----------------

extern "C" void kernel_launch(void* const* d_in, const int* in_sizes, int n_in,
                              void* d_out, int out_size, void* d_ws, size_t ws_size,
                              hipStream_t stream) {
    const float* x          = (const float*)d_in[0];
    const int*   edge_index = (const int*)d_in[1];
    const int*   e_src      = edge_index;            // row 0
    const int*   e_dst      = edge_index + N_EDGES;  // row 1
    const int*   src_idx    = (const int*)d_in[3];
    const int*   dst_idx    = (const int*)d_in[4];
    const float* w_emb      = (const float*)d_in[5];
    const float* b_emb      = (const float*)d_in[6];
    const float* wl0        = (const float*)d_in[8];
    const float* bl0        = (const float*)d_in[9];
    const float* wr0        = (const float*)d_in[10];
    const float* wl1        = (const float*)d_in[13];
    const float* bl1        = (const float*)d_in[14];
    const float* wr1        = (const float*)d_in[15];
    const float* wp1        = (const float*)d_in[18];
    const float* bp1        = (const float*)d_in[19];
    const float* wp2        = (const float*)d_in[20];
    const float* bp2        = (const float*)d_in[21];
    float* out = (float*)d_out;

    typedef __hip_bfloat16 bf16;
    const size_t NH  = (size_t)N_NODES * HID;
    const size_t NH1 = (size_t)(N_NODES + 1) * HID;   // +1 zero row (R17 pads)

    // workspace plan (~184 MB; ws proven >= 205 MB by R2)
    char* p = (char*)d_ws;
    bf16* h0   = (bf16*)p;  p += NH1 * 2;                      // 51.2 MB (+512B)
    bf16* h1   = (bf16*)p;  p += NH1 * 2;                      // 51.2 MB (+512B)
    bf16* agg  = (bf16*)p;  p += NH * 2;                       // 51.2 MB
    bf16* xb   = (bf16*)p;  p += (size_t)N_NODES * FEAT * 2;   // 25.6 MB
    bf16* wb   = (bf16*)p;  p += (size_t)W_TOTAL * 2;          // 1.1 MB
    bf16* wbp  = (bf16*)p;  p += (size_t)WP_TOTAL * 2;         // 0.6 MB (packed)
    p = (char*)(((uintptr_t)p + 255) & ~(uintptr_t)255);
    int* deg    = (int*)p; p += (size_t)N_NODES * 4;
    int* rowptr = (int*)p; p += (size_t)N_NODES * 4;
    int* ebuf   = (int*)p; p += (size_t)N_EDGES * 4;
    int* bsum   = (int*)p; p += 128 * 4;
    int* bpre   = (int*)p; p += 128 * 4;
    const size_t need = (size_t)(p - (char*)d_ws);

    if (ws_size < need) {   // visible failure, no fault
        zero_f32<<<(out_size + 255) / 256, 256, 0, stream>>>(out, out_size);
        return;
    }

    // aliases (regions dead by the time they're reused):
    bf16*  comb   = agg;         // [16384][1024] bf16 = 33.6 MB <= 51.2
    float* hidden = (float*)h1;  // [16384][256] fp32 = 16.8 MB <= 51.2

    // zero rows at h*[N_NODES] (gather pad targets); written once, never
    // touched by the GEMMs (they write rows < N_NODES only)
    zero_i32<<<1, 256, 0, stream>>>((int*)(h0 + NH), 128);
    zero_i32<<<1, 256, 0, stream>>>((int*)(h1 + NH), 128);

    // ---- CSR build ----
    zero_i32<<<(N_NODES + 255) / 256, 256, 0, stream>>>(deg, N_NODES);
    count_deg<<<(N_EDGES + 255) / 256, 256, 0, stream>>>(e_dst, deg, N_EDGES);
    csr_block_sums<<<SCAN_NB, 256, 0, stream>>>(deg, bsum);
    csr_scan_partials<<<1, 128, 0, stream>>>(bsum, bpre);
    csr_write_rowptr<<<SCAN_NB, 256, 0, stream>>>(deg, bpre, rowptr);
    fill_buckets<<<(N_EDGES + 255) / 256, 256, 0, stream>>>(e_src, e_dst, rowptr, ebuf, N_EDGES);
    sort_rows<<<(N_NODES + 255) / 256, 256, 0, stream>>>(rowptr, deg, ebuf);
    // rowptr now holds row_end per node

    // ---- bf16 conversions ----
    cvt_x<<<((N_NODES * FEAT / 4) + 255) / 256, 256, 0, stream>>>((const float4*)x, xb, N_NODES * FEAT / 4);
    cvt_w<<<(W_TOTAL + 255) / 256, 256, 0, stream>>>(w_emb, wl0, wr0, wl1, wr1, wp1, wb);
    cvt_w2<<<(WP_TOTAL + 255) / 256, 256, 0, stream>>>(w_emb, wl0, wr0, wl1, wr1, wbp);

    const int GX = 128;                     // 128 walkers x 4 cg = 512 blocks, 2/CU
    dim3 pgrid(GX, 4);                      // cg slow -> cg duplicates share XCD L2

    // ---- embedding: h0 = xb @ w_emb^T + b_emb  (KS=128) ----
    gemm_kc<128, false, bf16, false><<<pgrid, 256, 0, stream>>>(
        xb, nullptr, wbp + POF_EMB, nullptr, b_emb, h0, N_NODES, GX);

    // ---- layer 0: h1 = relu(agg@wl0^T + bl0 + h0@wr0^T)  (K-concat 512) ----
    gather_agg<<<(N_NODES + 7) / 8, 256, 0, stream>>>(h0, rowptr, deg, ebuf, agg);
    gemm_kc<256, true, bf16, true><<<pgrid, 256, 0, stream>>>(
        agg, h0, wbp + POF_L0, wbp + POF_R0, bl0, h1, N_NODES, GX);

    // ---- layer 1: h0 = relu(agg@wl1^T + bl1 + h1@wr1^T) ----
    gather_agg<<<(N_NODES + 7) / 8, 256, 0, stream>>>(h1, rowptr, deg, ebuf, agg);
    gemm_kc<256, true, bf16, true><<<pgrid, 256, 0, stream>>>(
        agg, h1, wbp + POF_L1, wbp + POF_R1, bl1, h0, N_NODES, GX);

    // ---- prediction head ----
    build_comb<<<N_LINKS, 256, 0, stream>>>(h0, src_idx, dst_idx, comb);
    mfma_gemm<2, false, float, true><<<(N_LINKS + 63) / 64, 256, 0, stream>>>(
        comb, nullptr, wb + WOF_P1, nullptr, bp1, hidden, N_LINKS, 4 * HID);
    pred_final<<<N_LINKS / 4, 256, 0, stream>>>(hidden, wp2, bp2, out);
}

// Round 11
// 491.385 us; speedup vs baseline: 1.1256x; 1.1256x over previous
//
#include <hip/hip_runtime.h>
#include <hip/hip_bf16.h>
#include <cstdint>
#include <type_traits>

#define N_NODES 100000
#define N_EDGES 500000
#define FEAT 128
#define HID 256
#define N_LINKS 16384

#define SCAN_CH 1024
#define SCAN_NB ((N_NODES + SCAN_CH - 1) / SCAN_CH)   // 98

typedef __attribute__((ext_vector_type(8))) short short8;     // 8 bf16 = 4 VGPRs
typedef __attribute__((ext_vector_type(4))) float floatx4;
typedef __attribute__((ext_vector_type(16))) float floatx16;  // 32x32 acc

// ---- scalar load/store ----
__device__ __forceinline__ float ldf(const float* p) { return *p; }
__device__ __forceinline__ float ldf(const __hip_bfloat16* p) { return __bfloat162float(*p); }
__device__ __forceinline__ void stf(float* p, float v) { *p = v; }
__device__ __forceinline__ void stf(__hip_bfloat16* p, float v) { *p = __float2bfloat16(v); }

// 4-wide bf16 load/store (8B)
__device__ __forceinline__ void load4(const __hip_bfloat16* p, float v[4]) {
    const uint2 q = *(const uint2*)p;
    v[0] = __uint_as_float(q.x << 16);
    v[1] = __uint_as_float(q.x & 0xffff0000u);
    v[2] = __uint_as_float(q.y << 16);
    v[3] = __uint_as_float(q.y & 0xffff0000u);
}
__device__ __forceinline__ void store4(__hip_bfloat16* p, const float v[4]) {
    __hip_bfloat16 b[4];
    b[0] = __float2bfloat16(v[0]); b[1] = __float2bfloat16(v[1]);
    b[2] = __float2bfloat16(v[2]); b[3] = __float2bfloat16(v[3]);
    *(uint2*)p = *(const uint2*)b;
}

// 8-wide bf16 load/store (16B)
__device__ __forceinline__ void load8(const __hip_bfloat16* p, float v[8]) {
    const uint4 q = *(const uint4*)p;
    v[0] = __uint_as_float(q.x << 16);
    v[1] = __uint_as_float(q.x & 0xffff0000u);
    v[2] = __uint_as_float(q.y << 16);
    v[3] = __uint_as_float(q.y & 0xffff0000u);
    v[4] = __uint_as_float(q.z << 16);
    v[5] = __uint_as_float(q.z & 0xffff0000u);
    v[6] = __uint_as_float(q.w << 16);
    v[7] = __uint_as_float(q.w & 0xffff0000u);
}
__device__ __forceinline__ void store8(__hip_bfloat16* p, const float v[8]) {
    __hip_bfloat16 b[8];
    #pragma unroll
    for (int i = 0; i < 8; i++) b[i] = __float2bfloat16(v[i]);
    *(uint4*)p = *(const uint4*)b;
}

// unpack a raw 16B bf16x8 chunk and accumulate into acc[8]
__device__ __forceinline__ void acc8(const uint4& q, float a[8]) {
    a[0] += __uint_as_float(q.x << 16);
    a[1] += __uint_as_float(q.x & 0xffff0000u);
    a[2] += __uint_as_float(q.y << 16);
    a[3] += __uint_as_float(q.y & 0xffff0000u);
    a[4] += __uint_as_float(q.z << 16);
    a[5] += __uint_as_float(q.z & 0xffff0000u);
    a[6] += __uint_as_float(q.w << 16);
    a[7] += __uint_as_float(q.w & 0xffff0000u);
}

// async global->LDS, 16B per lane; LDS dest = wave-uniform base + lane*16
__device__ __forceinline__ void gload_lds16(const short* g, short* lds) {
    __builtin_amdgcn_global_load_lds(
        reinterpret_cast<const __attribute__((address_space(1))) unsigned int*>(
            reinterpret_cast<uintptr_t>(g)),
        reinterpret_cast<__attribute__((address_space(3))) unsigned int*>(
            reinterpret_cast<uintptr_t>(lds)),
        16, 0, 0);
}

// defensive: any out-of-range index becomes 0 (wrong answer, not a fault)
__device__ __forceinline__ int clampi(int v, int n) { return ((unsigned)v < (unsigned)n) ? v : 0; }

// ---------------- utility ----------------

__global__ void zero_f32(float* p, int n) {
    int i = blockIdx.x * blockDim.x + threadIdx.x;
    if (i < n) p[i] = 0.0f;
}
__global__ void zero_i32(int* p, int n) {
    int i = blockIdx.x * blockDim.x + threadIdx.x;
    if (i < n) p[i] = 0;
}

// x (float4-wide) -> bf16
__global__ void cvt_x(const float4* __restrict__ x, __hip_bfloat16* __restrict__ xb, int n4) {
    int i = blockIdx.x * blockDim.x + threadIdx.x;
    if (i >= n4) return;
    float4 v = x[i];
    float a[4] = {v.x, v.y, v.z, v.w};
    store4(&xb[(size_t)i * 4], a);
}

// weights -> contiguous bf16 buffer, row-major (used by pred head p1 only now)
#define WOF_EMB 0
#define WOF_L0  32768
#define WOF_R0  98304
#define WOF_L1  163840
#define WOF_R1  229376
#define WOF_P1  294912
#define W_TOTAL 557056
__global__ void cvt_w(const float* __restrict__ w_emb, const float* __restrict__ wl0,
                      const float* __restrict__ wr0, const float* __restrict__ wl1,
                      const float* __restrict__ wr1, const float* __restrict__ wp1,
                      __hip_bfloat16* __restrict__ wb) {
    int i = blockIdx.x * blockDim.x + threadIdx.x;
    if (i >= W_TOTAL) return;
    float v;
    if      (i < WOF_L0) v = w_emb[i - WOF_EMB];
    else if (i < WOF_R0) v = wl0[i - WOF_L0];
    else if (i < WOF_L1) v = wr0[i - WOF_R0];
    else if (i < WOF_R1) v = wl1[i - WOF_L1];
    else if (i < WOF_P1) v = wr1[i - WOF_R1];
    else                 v = wp1[i - WOF_P1];
    wb[i] = __float2bfloat16(v);
}

// R13: packed "LDS image" layout for the gemm_kc staged B operand.
// Per matrix: [KS/8 ksegs][256 cols][8 bf16], element (kseg, n, j) = W[n][kseg*8+j].
#define POF_EMB 0
#define POF_L0  32768
#define POF_R0  98304
#define POF_L1  163840
#define POF_R1  229376
#define WP_TOTAL 294912
__global__ void cvt_w2(const float* __restrict__ w_emb, const float* __restrict__ wl0,
                       const float* __restrict__ wr0, const float* __restrict__ wl1,
                       const float* __restrict__ wr1, __hip_bfloat16* __restrict__ wbp) {
    int i = blockIdx.x * blockDim.x + threadIdx.x;
    if (i >= WP_TOTAL) return;
    const float* src; int off, ks;
    if      (i < POF_L0) { src = w_emb; off = POF_EMB; ks = 128; }
    else if (i < POF_R0) { src = wl0;   off = POF_L0;  ks = 256; }
    else if (i < POF_L1) { src = wr0;   off = POF_R0;  ks = 256; }
    else if (i < POF_R1) { src = wl1;   off = POF_L1;  ks = 256; }
    else                 { src = wr1;   off = POF_R1;  ks = 256; }
    int o = i - off;
    int kseg = o >> 11;        // / (256*8)
    int rem  = o & 2047;
    int n = rem >> 3, j = rem & 7;
    wbp[i] = __float2bfloat16(src[n * ks + kseg * 8 + j]);
}

// ---------------- CSR build ----------------

__global__ void count_deg(const int* __restrict__ dst, int* __restrict__ deg, int nE) {
    int e = blockIdx.x * blockDim.x + threadIdx.x;
    if (e < nE) atomicAdd(&deg[clampi(dst[e], N_NODES)], 1);
}

__global__ __launch_bounds__(256) void csr_block_sums(const int* __restrict__ deg, int* __restrict__ bsum) {
    __shared__ int red[256];
    int b = blockIdx.x, t = threadIdx.x;
    int s = 0;
    #pragma unroll
    for (int j = 0; j < 4; j++) {
        int i = b * SCAN_CH + t + j * 256;
        if (i < N_NODES) s += deg[i];
    }
    red[t] = s; __syncthreads();
    for (int o = 128; o > 0; o >>= 1) {
        if (t < o) red[t] += red[t + o];
        __syncthreads();
    }
    if (t == 0) bsum[b] = red[0];
}

__global__ __launch_bounds__(128) void csr_scan_partials(const int* __restrict__ bsum, int* __restrict__ bpre) {
    __shared__ int sc[128];
    int t = threadIdx.x;
    int v = (t < SCAN_NB) ? bsum[t] : 0;
    sc[t] = v; __syncthreads();
    for (int o = 1; o < 128; o <<= 1) {
        int x = (t >= o) ? sc[t - o] : 0;
        __syncthreads();
        sc[t] += x;
        __syncthreads();
    }
    if (t < SCAN_NB) bpre[t] = sc[t] - v;   // exclusive
}

__global__ __launch_bounds__(256) void csr_write_rowptr(const int* __restrict__ deg,
                                                        const int* __restrict__ bpre,
                                                        int* __restrict__ rowptr) {
    __shared__ int sc[256];
    int b = blockIdx.x, t = threadIdx.x;
    int base = bpre[b];
    int i0 = b * SCAN_CH + t * 4;
    int d[4];
    int s = 0;
    #pragma unroll
    for (int j = 0; j < 4; j++) {
        d[j] = (i0 + j < N_NODES) ? deg[i0 + j] : 0;
        s += d[j];
    }
    sc[t] = s; __syncthreads();
    for (int o = 1; o < 256; o <<= 1) {
        int x = (t >= o) ? sc[t - o] : 0;
        __syncthreads();
        sc[t] += x;
        __syncthreads();
    }
    int pre = base + sc[t] - s;
    #pragma unroll
    for (int j = 0; j < 4; j++) {
        if (i0 + j < N_NODES) rowptr[i0 + j] = pre;
        pre += d[j];
    }
}

__global__ void fill_buckets(const int* __restrict__ src, const int* __restrict__ dst,
                             int* __restrict__ rowptr, int* __restrict__ ebuf, int nE) {
    int e = blockIdx.x * blockDim.x + threadIdx.x;
    if (e >= nE) return;
    int d = clampi(dst[e], N_NODES);
    int pos = atomicAdd(&rowptr[d], 1);
    if (pos < nE) ebuf[pos] = clampi(src[e], N_NODES);
}

// DETERMINISM: fill_buckets slots edges in atomic arrival order (varies per run).
// Sorting each row makes summation order a pure function of the input multiset
// -> bit-exact output every call.
__global__ void sort_rows(const int* __restrict__ rowend, const int* __restrict__ deg,
                          int* __restrict__ ebuf) {
    int n = blockIdx.x * blockDim.x + threadIdx.x;
    if (n >= N_NODES) return;
    int end = rowend[n];
    int start = end - deg[n];
    for (int i = start + 1; i < end; i++) {          // insertion sort (mean deg ~5)
        int key = ebuf[i];
        int j = i - 1;
        while (j >= start && ebuf[j] > key) { ebuf[j + 1] = ebuf[j]; j--; }
        ebuf[j + 1] = key;
    }
}

// ---------------- gather aggregation ----------------
// R17: branch-free 8-deep batch; pad slots load the zero row at h[N_NODES]
// and are added unconditionally (+0.0, exact). Order fixed (self, then
// ascending-e slots incl. zero pads) -> bit-exact across runs.
// Grid: 12500 blocks x 8 nodes; half-per-node, 16B/lane.

__global__ __launch_bounds__(256) void gather_agg(const __hip_bfloat16* __restrict__ h,
                                                  const int* __restrict__ rowend,
                                                  const int* __restrict__ deg,
                                                  const int* __restrict__ ebuf,
                                                  __hip_bfloat16* __restrict__ agg) {
    int wave = threadIdx.x >> 6, lane = threadIdx.x & 63;
    int half = lane >> 5, l32 = lane & 31;
    int n = blockIdx.x * 8 + wave * 2 + half;       // 8 nodes per 256-thr block
    bool active = (n < N_NODES);
    int nn = active ? n : 0;
    int dg  = deg[nn];
    int end = rowend[nn];
    int start = end - dg;
    if (!active) { end = 0; start = 0; dg = 0; }

    float acc[8];
    {
        float sv[8];
        load8(&h[(long long)nn * HID + l32 * 8], sv);   // self row
        #pragma unroll
        for (int k = 0; k < 8; k++) acc[k] = sv[k];
    }

    for (int e = start; e < end; e += 8) {
        int cnt = end - e;                              // >= 1 inside loop
        uint4 raw[8];
        #pragma unroll
        for (int i = 0; i < 8; i++) {
            int t = e + i; t = (t < end) ? t : (end - 1);   // in-bounds ebuf idx
            int idx = ebuf[t];
            int s = (i < cnt) ? idx : N_NODES;              // pad -> zero row
            raw[i] = *(const uint4*)&h[(long long)s * HID + l32 * 8];
        }
        #pragma unroll
        for (int i = 0; i < 8; i++) acc8(raw[i], acc);      // pads add +0.0
    }

    float inv = 1.0f / (float)(dg + 1);
    #pragma unroll
    for (int k = 0; k < 8; k++) acc[k] *= inv;
    if (active) store8(&agg[(long long)n * HID + l32 * 8], acc);
}

// ============ R13/R22: K-concat LDS-staged GEMM, 128-col wide tile ============
// C = [A1|A2] @ [B1|B2]^T as ONE K=512 GEMM.
// R21 post-mortem: counted-vmcnt + sched_barrier regressed (m141 reproduced);
// reverted to the R17 2-buffer __syncthreads pipeline. R22 instead RAISES
// ARITHMETIC INTENSITY PER BARRIER: block = 128 rows x 128 cols (cg in {0,1}),
// 4 waves, each 32 rows x 128 cols -> acc[4] of 32x32; per K-step 16 MFMA
// (was 8) under the same one-barrier drain; A-staging per MFMA halves
// (total staged bytes 1.2 GB -> 0.8 GB per dual GEMM).
// Grid (GX=256, 2): 512 blocks = 2/CU; cg duplicates 256 apart in linear id,
// 256%8==0 -> same XCD L2 (R19/R20-verified locality rule). LDS 64 KB.
// MFMA order per acc unchanged (t ascending, k16 ascending) -> bit-exact.

template <int KS, bool DUAL, typename TC, bool RELU>
__global__ __launch_bounds__(256, 2) void gemm_kc(const __hip_bfloat16* __restrict__ A1,
                                                  const __hip_bfloat16* __restrict__ A2,
                                                  const __hip_bfloat16* __restrict__ Bp1,
                                                  const __hip_bfloat16* __restrict__ Bp2,
                                                  const float* __restrict__ bias,
                                                  TC* __restrict__ C, int M, int GX) {
    const int N = 256;
    const int NSTEP = (DUAL ? 2 : 1) * KS / 64;       // 64-wide K steps
    __shared__ __align__(16) short As[2][128 * 64];   // 2 x 16 KB
    __shared__ __align__(16) short Bs[2][64 * 128];   // 2 x 16 KB  (64 KB total)

    const int tid = threadIdx.x;
    const int w = tid >> 6, lane = tid & 63;
    const int half = lane >> 5, l32 = lane & 31;
    const int cg = blockIdx.y;                        // 0..1 (128-col groups)

    const short* A1s = (const short*)A1;
    const short* A2s = (const short*)A2;
    const short* B1s = (const short*)Bp1;
    const short* B2s = (const short*)Bp2;

    const int NT = (M + 127) / 128;
    for (int tile = blockIdx.x; tile < NT; tile += GX) {
        const int row0 = tile * 128;

        // stage K-step t: A 4 gloads/thread, B 4 gloads/thread
        auto stage = [&](int buf, int t) {
            const short* Asrc; const short* Bsrc; int kl;
            if (!DUAL || t < KS / 64) { Asrc = A1s; Bsrc = B1s; kl = t * 64; }
            else                      { Asrc = A2s; Bsrc = B2s; kl = t * 64 - KS; }
            #pragma unroll
            for (int i = 0; i < 4; i++) {
                int idx = i * 256 + tid;             // 0..1023
                int row = idx >> 3, b16 = idx & 7;
                int gr = row0 + row; if (gr >= M) gr = M - 1;
                gload_lds16(Asrc + (size_t)gr * KS + kl + ((b16 ^ (row & 7)) * 8),
                            (short*)&As[buf][idx * 8]);
            }
            #pragma unroll
            for (int i = 0; i < 4; i++) {
                int idx = i * 256 + tid;             // 0..1023
                int kseg = idx >> 7, col = idx & 127;
                gload_lds16(Bsrc + ((size_t)((kl >> 3) + kseg) * 256 + cg * 128 + col) * 8,
                            (short*)&Bs[buf][idx * 8]);
            }
        };

        floatx16 acc[4] = {};
        int cur = 0;
        stage(0, 0);
        __syncthreads();

        for (int t = 0; t < NSTEP; t++) {
            if (t + 1 < NSTEP) stage(cur ^ 1, t + 1);   // async, overlaps compute

            const int arow = w * 32 + l32;
            #pragma unroll
            for (int k16 = 0; k16 < 4; k16++) {
                int e = k16 * 2 + half;
                short8 a = *(const short8*)&As[cur][(arow * 8 + (e ^ (l32 & 7))) * 8];
                #pragma unroll
                for (int ct = 0; ct < 4; ct++) {
                    short8 b = *(const short8*)&Bs[cur][(e * 128 + ct * 32 + l32) * 8];
                    acc[ct] = __builtin_amdgcn_mfma_f32_32x32x16_bf16(a, b, acc[ct], 0, 0, 0);
                }
            }
            __syncthreads();                            // vmcnt(0)+lgkm+barrier
            cur ^= 1;
        }

        // epilogue: C/D col = lane&31, row = (reg&3) + 8*(reg>>2) + 4*half
        #pragma unroll
        for (int ct = 0; ct < 4; ct++) {
            int c = cg * 128 + ct * 32 + l32;
            float bc = bias[c];
            #pragma unroll
            for (int reg = 0; reg < 16; reg++) {
                int rr = row0 + w * 32 + (reg & 3) + 8 * (reg >> 2) + 4 * half;
                if (rr < M) {
                    float v = acc[ct][reg] + bc;
                    if (RELU) v = fmaxf(v, 0.0f);
                    stf(&C[(size_t)rr * N + c], v);
                }
            }
        }
    }
}

// ---------------- rolling-stage MFMA GEMM (K=1024 pred head, 16x16x32) ----------------

template <int RT, bool DUAL, typename TC, bool RELU>
__global__ __launch_bounds__(256, 2) void mfma_gemm(const __hip_bfloat16* __restrict__ A1,
                                                    const __hip_bfloat16* __restrict__ A2,
                                                    const __hip_bfloat16* __restrict__ B1,
                                                    const __hip_bfloat16* __restrict__ B2,
                                                    const float* __restrict__ bias,
                                                    TC* __restrict__ C, int M, int K) {
    const int N = 256;
    const int SZ = 4 * 256 * 8;
    __shared__ __align__(16) short Bs[DUAL ? 4 : 2][SZ];

    int w = threadIdx.x >> 6, lane = threadIdx.x & 63;
    int quad = lane >> 4, l16 = lane & 15;
    int wr = w >> 1, wc = w & 1;
    const int WROWS = RT * 16;
    int row0 = blockIdx.x * (2 * WROWS) + wr * WROWS;
    int colbase = wc * 128;

    const short* A1s = (const short*)A1;
    const short* A2s = (const short*)A2;
    const short* B1s = (const short*)B1;
    const short* B2s = (const short*)B2;

    floatx4 acc[RT][8] = {};

    int r[RT];
    #pragma unroll
    for (int i = 0; i < RT; i++) {
        int rr = row0 + i * 16 + l16;
        r[i] = rr < M ? rr : M - 1;
    }
    int scol = threadIdx.x;
    int ldsoff = (w * 64) * 8;

    short8 a1c[RT], a2c[RT], a1n[RT], a2n[RT];

    #pragma unroll
    for (int q = 0; q < 4; q++) {
        gload_lds16(B1s + (size_t)scol * K + q * 8, &Bs[0][q * 256 * 8 + ldsoff]);
        if (DUAL)
            gload_lds16(B2s + (size_t)scol * K + q * 8, &Bs[2][q * 256 * 8 + ldsoff]);
    }
    {
        int ka = quad * 8;
        #pragma unroll
        for (int i = 0; i < RT; i++) {
            a1c[i] = *(const short8*)(A1s + (size_t)r[i] * K + ka);
            if (DUAL) a2c[i] = *(const short8*)(A2s + (size_t)r[i] * K + ka);
        }
    }
    __syncthreads();

    const int NK = K / 32;
    int cur = 0;
    for (int k = 0; k < NK; k++) {
        if (k + 1 < NK) {
            int k0n = (k + 1) * 32;
            #pragma unroll
            for (int q = 0; q < 4; q++) {
                gload_lds16(B1s + (size_t)scol * K + k0n + q * 8,
                            &Bs[cur ^ 1][q * 256 * 8 + ldsoff]);
                if (DUAL)
                    gload_lds16(B2s + (size_t)scol * K + k0n + q * 8,
                                &Bs[2 + (cur ^ 1)][q * 256 * 8 + ldsoff]);
            }
            int ka = k0n + quad * 8;
            #pragma unroll
            for (int i = 0; i < RT; i++) {
                a1n[i] = *(const short8*)(A1s + (size_t)r[i] * K + ka);
                if (DUAL) a2n[i] = *(const short8*)(A2s + (size_t)r[i] * K + ka);
            }
        }

        short8 b1[8], b2[8];
        #pragma unroll
        for (int ct = 0; ct < 8; ct++) {
            int col = colbase + ct * 16 + l16;
            b1[ct] = *(const short8*)&Bs[cur][(quad * 256 + col) * 8];
            if (DUAL) b2[ct] = *(const short8*)&Bs[2 + cur][(quad * 256 + col) * 8];
        }
        #pragma unroll
        for (int i = 0; i < RT; i++) {
            #pragma unroll
            for (int ct = 0; ct < 8; ct++) {
                acc[i][ct] = __builtin_amdgcn_mfma_f32_16x16x32_bf16(a1c[i], b1[ct], acc[i][ct], 0, 0, 0);
                if (DUAL)
                    acc[i][ct] = __builtin_amdgcn_mfma_f32_16x16x32_bf16(a2c[i], b2[ct], acc[i][ct], 0, 0, 0);
            }
        }
        __syncthreads();
        cur ^= 1;
        #pragma unroll
        for (int i = 0; i < RT; i++) {
            a1c[i] = a1n[i];
            if (DUAL) a2c[i] = a2n[i];
        }
    }

    #pragma unroll
    for (int rt = 0; rt < RT; rt++) {
        #pragma unroll
        for (int ct = 0; ct < 8; ct++) {
            int c = colbase + ct * 16 + l16;
            float bc = bias[c];
            #pragma unroll
            for (int i = 0; i < 4; i++) {
                int rr = row0 + rt * 16 + quad * 4 + i;
                if (rr < M) {
                    float v = acc[rt][ct][i] + bc;
                    if (RELU) v = fmaxf(v, 0.0f);
                    stf(&C[(size_t)rr * N + c], v);
                }
            }
        }
    }
}

// ---------------- prediction head ----------------

__global__ __launch_bounds__(256) void build_comb(const __hip_bfloat16* __restrict__ h,
                                                  const int* __restrict__ src_idx,
                                                  const int* __restrict__ dst_idx,
                                                  __hip_bfloat16* __restrict__ comb) {
    int row = blockIdx.x;
    int t = threadIdx.x;
    int s = clampi(src_idx[row], N_NODES);
    int d = clampi(dst_idx[row], N_NODES);
    float sv = ldf(&h[(long long)s * HID + t]);
    float dv = ldf(&h[(long long)d * HID + t]);
    __hip_bfloat16* cr = &comb[(long long)row * (4 * HID)];
    stf(&cr[t], sv);
    stf(&cr[HID + t], dv);
    stf(&cr[2 * HID + t], sv * dv);
    stf(&cr[3 * HID + t], fabsf(sv - dv));
}

__global__ __launch_bounds__(256) void pred_final(const float* __restrict__ hidden,
                                                  const float* __restrict__ wp2,
                                                  const float* __restrict__ bp2,
                                                  float* __restrict__ out) {
    int wave = threadIdx.x >> 6;
    int lane = threadIdx.x & 63;
    int row = blockIdx.x * 4 + wave;
    if (row >= N_LINKS) return;
    const float4 hv = *(const float4*)&hidden[(long long)row * HID + lane * 4];
    const float4 wv = *(const float4*)&wp2[lane * 4];
    float v = hv.x * wv.x + hv.y * wv.y + hv.z * wv.z + hv.w * wv.w;
    #pragma unroll
    for (int off = 32; off > 0; off >>= 1) v += __shfl_down(v, off, 64);
    if (lane == 0) out[row] = 1.0f / (1.0f + expf(-(v + bp2[0])));
}

// ---------------- launch ----------------

extern "C" void kernel_launch(void* const* d_in, const int* in_sizes, int n_in,
                              void* d_out, int out_size, void* d_ws, size_t ws_size,
                              hipStream_t stream) {
    const float* x          = (const float*)d_in[0];
    const int*   edge_index = (const int*)d_in[1];
    const int*   e_src      = edge_index;            // row 0
    const int*   e_dst      = edge_index + N_EDGES;  // row 1
    const int*   src_idx    = (const int*)d_in[3];
    const int*   dst_idx    = (const int*)d_in[4];
    const float* w_emb      = (const float*)d_in[5];
    const float* b_emb      = (const float*)d_in[6];
    const float* wl0        = (const float*)d_in[8];
    const float* bl0        = (const float*)d_in[9];
    const float* wr0        = (const float*)d_in[10];
    const float* wl1        = (const float*)d_in[13];
    const float* bl1        = (const float*)d_in[14];
    const float* wr1        = (const float*)d_in[15];
    const float* wp1        = (const float*)d_in[18];
    const float* bp1        = (const float*)d_in[19];
    const float* wp2        = (const float*)d_in[20];
    const float* bp2        = (const float*)d_in[21];
    float* out = (float*)d_out;

    typedef __hip_bfloat16 bf16;
    const size_t NH  = (size_t)N_NODES * HID;
    const size_t NH1 = (size_t)(N_NODES + 1) * HID;   // +1 zero row (R17 pads)

    // workspace plan (~184 MB; ws proven >= 205 MB by R2)
    char* p = (char*)d_ws;
    bf16* h0   = (bf16*)p;  p += NH1 * 2;                      // 51.2 MB (+512B)
    bf16* h1   = (bf16*)p;  p += NH1 * 2;                      // 51.2 MB (+512B)
    bf16* agg  = (bf16*)p;  p += NH * 2;                       // 51.2 MB
    bf16* xb   = (bf16*)p;  p += (size_t)N_NODES * FEAT * 2;   // 25.6 MB
    bf16* wb   = (bf16*)p;  p += (size_t)W_TOTAL * 2;          // 1.1 MB
    bf16* wbp  = (bf16*)p;  p += (size_t)WP_TOTAL * 2;         // 0.6 MB (packed)
    p = (char*)(((uintptr_t)p + 255) & ~(uintptr_t)255);
    int* deg    = (int*)p; p += (size_t)N_NODES * 4;
    int* rowptr = (int*)p; p += (size_t)N_NODES * 4;
    int* ebuf   = (int*)p; p += (size_t)N_EDGES * 4;
    int* bsum   = (int*)p; p += 128 * 4;
    int* bpre   = (int*)p; p += 128 * 4;
    const size_t need = (size_t)(p - (char*)d_ws);

    if (ws_size < need) {   // visible failure, no fault
        zero_f32<<<(out_size + 255) / 256, 256, 0, stream>>>(out, out_size);
        return;
    }

    // aliases (regions dead by the time they're reused):
    bf16*  comb   = agg;         // [16384][1024] bf16 = 33.6 MB <= 51.2
    float* hidden = (float*)h1;  // [16384][256] fp32 = 16.8 MB <= 51.2

    // zero rows at h*[N_NODES] (gather pad targets); written once, never
    // touched by the GEMMs (they write rows < N_NODES only)
    zero_i32<<<1, 256, 0, stream>>>((int*)(h0 + NH), 128);
    zero_i32<<<1, 256, 0, stream>>>((int*)(h1 + NH), 128);

    // ---- CSR build ----
    zero_i32<<<(N_NODES + 255) / 256, 256, 0, stream>>>(deg, N_NODES);
    count_deg<<<(N_EDGES + 255) / 256, 256, 0, stream>>>(e_dst, deg, N_EDGES);
    csr_block_sums<<<SCAN_NB, 256, 0, stream>>>(deg, bsum);
    csr_scan_partials<<<1, 128, 0, stream>>>(bsum, bpre);
    csr_write_rowptr<<<SCAN_NB, 256, 0, stream>>>(deg, bpre, rowptr);
    fill_buckets<<<(N_EDGES + 255) / 256, 256, 0, stream>>>(e_src, e_dst, rowptr, ebuf, N_EDGES);
    sort_rows<<<(N_NODES + 255) / 256, 256, 0, stream>>>(rowptr, deg, ebuf);
    // rowptr now holds row_end per node

    // ---- bf16 conversions ----
    cvt_x<<<((N_NODES * FEAT / 4) + 255) / 256, 256, 0, stream>>>((const float4*)x, xb, N_NODES * FEAT / 4);
    cvt_w<<<(W_TOTAL + 255) / 256, 256, 0, stream>>>(w_emb, wl0, wr0, wl1, wr1, wp1, wb);
    cvt_w2<<<(WP_TOTAL + 255) / 256, 256, 0, stream>>>(w_emb, wl0, wr0, wl1, wr1, wbp);

    const int GX = 256;                     // 256 walkers x 2 cg = 512 blocks, 2/CU
    dim3 pgrid(GX, 2);                      // cg slow; duplicates 256 apart ->
                                            // same XCD L2 (256 % 8 == 0)

    // ---- embedding: h0 = xb @ w_emb^T + b_emb  (KS=128) ----
    gemm_kc<128, false, bf16, false><<<pgrid, 256, 0, stream>>>(
        xb, nullptr, wbp + POF_EMB, nullptr, b_emb, h0, N_NODES, GX);

    // ---- layer 0: h1 = relu(agg@wl0^T + bl0 + h0@wr0^T)  (K-concat 512) ----
    gather_agg<<<(N_NODES + 7) / 8, 256, 0, stream>>>(h0, rowptr, deg, ebuf, agg);
    gemm_kc<256, true, bf16, true><<<pgrid, 256, 0, stream>>>(
        agg, h0, wbp + POF_L0, wbp + POF_R0, bl0, h1, N_NODES, GX);

    // ---- layer 1: h0 = relu(agg@wl1^T + bl1 + h1@wr1^T) ----
    gather_agg<<<(N_NODES + 7) / 8, 256, 0, stream>>>(h1, rowptr, deg, ebuf, agg);
    gemm_kc<256, true, bf16, true><<<pgrid, 256, 0, stream>>>(
        agg, h1, wbp + POF_L1, wbp + POF_R1, bl1, h0, N_NODES, GX);

    // ---- prediction head ----
    build_comb<<<N_LINKS, 256, 0, stream>>>(h0, src_idx, dst_idx, comb);
    mfma_gemm<2, false, float, true><<<(N_LINKS + 63) / 64, 256, 0, stream>>>(
        comb, nullptr, wb + WOF_P1, nullptr, bp1, hidden, N_LINKS, 4 * HID);
    pred_final<<<N_LINKS / 4, 256, 0, stream>>>(hidden, wp2, bp2, out);
}

// Round 12
// 460.189 us; speedup vs baseline: 1.2019x; 1.0678x over previous
//
#include <hip/hip_runtime.h>
#include <hip/hip_bf16.h>
#include <cstdint>
#include <type_traits>

#define N_NODES 100000
#define N_EDGES 500000
#define FEAT 128
#define HID 256
#define N_LINKS 16384
#define BCAP 32   // bucket capacity; deg ~ Poisson(5), P(>32) ~ 1e-15

typedef __attribute__((ext_vector_type(8))) short short8;     // 8 bf16 = 4 VGPRs
typedef __attribute__((ext_vector_type(4))) float floatx4;
typedef __attribute__((ext_vector_type(16))) float floatx16;  // 32x32 acc

// ---- scalar load/store ----
__device__ __forceinline__ float ldf(const float* p) { return *p; }
__device__ __forceinline__ float ldf(const __hip_bfloat16* p) { return __bfloat162float(*p); }
__device__ __forceinline__ void stf(float* p, float v) { *p = v; }
__device__ __forceinline__ void stf(__hip_bfloat16* p, float v) { *p = __float2bfloat16(v); }

// 4-wide bf16 load/store (8B)
__device__ __forceinline__ void load4(const __hip_bfloat16* p, float v[4]) {
    const uint2 q = *(const uint2*)p;
    v[0] = __uint_as_float(q.x << 16);
    v[1] = __uint_as_float(q.x & 0xffff0000u);
    v[2] = __uint_as_float(q.y << 16);
    v[3] = __uint_as_float(q.y & 0xffff0000u);
}
__device__ __forceinline__ void store4(__hip_bfloat16* p, const float v[4]) {
    __hip_bfloat16 b[4];
    b[0] = __float2bfloat16(v[0]); b[1] = __float2bfloat16(v[1]);
    b[2] = __float2bfloat16(v[2]); b[3] = __float2bfloat16(v[3]);
    *(uint2*)p = *(const uint2*)b;
}

// 8-wide bf16 load/store (16B)
__device__ __forceinline__ void load8(const __hip_bfloat16* p, float v[8]) {
    const uint4 q = *(const uint4*)p;
    v[0] = __uint_as_float(q.x << 16);
    v[1] = __uint_as_float(q.x & 0xffff0000u);
    v[2] = __uint_as_float(q.y << 16);
    v[3] = __uint_as_float(q.y & 0xffff0000u);
    v[4] = __uint_as_float(q.z << 16);
    v[5] = __uint_as_float(q.z & 0xffff0000u);
    v[6] = __uint_as_float(q.w << 16);
    v[7] = __uint_as_float(q.w & 0xffff0000u);
}
__device__ __forceinline__ void store8(__hip_bfloat16* p, const float v[8]) {
    __hip_bfloat16 b[8];
    #pragma unroll
    for (int i = 0; i < 8; i++) b[i] = __float2bfloat16(v[i]);
    *(uint4*)p = *(const uint4*)b;
}

// unpack a raw 16B bf16x8 chunk and accumulate into acc[8]
__device__ __forceinline__ void acc8(const uint4& q, float a[8]) {
    a[0] += __uint_as_float(q.x << 16);
    a[1] += __uint_as_float(q.x & 0xffff0000u);
    a[2] += __uint_as_float(q.y << 16);
    a[3] += __uint_as_float(q.y & 0xffff0000u);
    a[4] += __uint_as_float(q.z << 16);
    a[5] += __uint_as_float(q.z & 0xffff0000u);
    a[6] += __uint_as_float(q.w << 16);
    a[7] += __uint_as_float(q.w & 0xffff0000u);
}

// async global->LDS, 16B per lane; LDS dest = wave-uniform base + lane*16
__device__ __forceinline__ void gload_lds16(const short* g, short* lds) {
    __builtin_amdgcn_global_load_lds(
        reinterpret_cast<const __attribute__((address_space(1))) unsigned int*>(
            reinterpret_cast<uintptr_t>(g)),
        reinterpret_cast<__attribute__((address_space(3))) unsigned int*>(
            reinterpret_cast<uintptr_t>(lds)),
        16, 0, 0);
}

// defensive: any out-of-range index becomes 0 (wrong answer, not a fault)
__device__ __forceinline__ int clampi(int v, int n) { return ((unsigned)v < (unsigned)n) ? v : 0; }

// ---------------- utility ----------------

__global__ void zero_f32(float* p, int n) {
    int i = blockIdx.x * blockDim.x + threadIdx.x;
    if (i < n) p[i] = 0.0f;
}

// R23: one init kernel: deg=0 + both gather pad rows (h0/h1 row N_NODES)
__global__ void init_misc(int* __restrict__ deg, int* __restrict__ h0pad,
                          int* __restrict__ h1pad) {
    int i = blockIdx.x * blockDim.x + threadIdx.x;
    if (i < N_NODES) deg[i] = 0;
    if (i < 128) { h0pad[i] = 0; h1pad[i] = 0; }
}

// x (float4-wide) -> bf16
__global__ void cvt_x(const float4* __restrict__ x, __hip_bfloat16* __restrict__ xb, int n4) {
    int i = blockIdx.x * blockDim.x + threadIdx.x;
    if (i >= n4) return;
    float4 v = x[i];
    float a[4] = {v.x, v.y, v.z, v.w};
    store4(&xb[(size_t)i * 4], a);
}

// R13 packed "LDS image" layout for the gemm_kc staged B operand.
// Per matrix: [KS/8 ksegs][256 cols][8 bf16], element (kseg, n, j) = W[n][kseg*8+j].
#define POF_EMB 0
#define POF_L0  32768
#define POF_R0  98304
#define POF_L1  163840
#define POF_R1  229376
#define WP_TOTAL 294912
#define WP1_N   262144     // wp1: [256][1024] row-major bf16 (pred-head B)
// R23: single conversion kernel: packed image (5 matrices) + wp1 row-major
__global__ void cvt_wall(const float* __restrict__ w_emb, const float* __restrict__ wl0,
                         const float* __restrict__ wr0, const float* __restrict__ wl1,
                         const float* __restrict__ wr1, const float* __restrict__ wp1,
                         __hip_bfloat16* __restrict__ wbp, __hip_bfloat16* __restrict__ wbp1) {
    int i = blockIdx.x * blockDim.x + threadIdx.x;
    if (i < WP_TOTAL) {
        const float* src; int off, ks;
        if      (i < POF_L0) { src = w_emb; off = POF_EMB; ks = 128; }
        else if (i < POF_R0) { src = wl0;   off = POF_L0;  ks = 256; }
        else if (i < POF_L1) { src = wr0;   off = POF_R0;  ks = 256; }
        else if (i < POF_R1) { src = wl1;   off = POF_L1;  ks = 256; }
        else                 { src = wr1;   off = POF_R1;  ks = 256; }
        int o = i - off;
        int kseg = o >> 11;        // / (256*8)
        int rem  = o & 2047;
        int n = rem >> 3, j = rem & 7;
        wbp[i] = __float2bfloat16(src[n * ks + kseg * 8 + j]);
    } else if (i < WP_TOTAL + WP1_N) {
        int j = i - WP_TOTAL;
        wbp1[j] = __float2bfloat16(wp1[j]);
    }
}

// ---------------- bucketed adjacency build (R23: replaces CSR scan chain) ----------------
// ebuf[n*BCAP + pos] slots; pos from atomicAdd(&deg[n]) -> count+fill in ONE
// kernel (old count_deg + 3-kernel prefix scan + fill_buckets collapsed).
// Arrival order varies per run -> sort_rows normalizes (same order as the
// CSR+sort path of R17: ascending src per node) -> bit-exact aggregation.

__global__ void fill_buckets(const int* __restrict__ src, const int* __restrict__ dst,
                             int* __restrict__ deg, int* __restrict__ ebuf, int nE) {
    int e = blockIdx.x * blockDim.x + threadIdx.x;
    if (e >= nE) return;
    int d = clampi(dst[e], N_NODES);
    int pos = atomicAdd(&deg[d], 1);
    if (pos < BCAP) ebuf[d * BCAP + pos] = clampi(src[e], N_NODES);
}

__global__ void sort_rows(const int* __restrict__ deg, int* __restrict__ ebuf) {
    int n = blockIdx.x * blockDim.x + threadIdx.x;
    if (n >= N_NODES) return;
    int dg = deg[n]; if (dg > BCAP) dg = BCAP;
    int start = n * BCAP, end = start + dg;
    for (int i = start + 1; i < end; i++) {          // insertion sort (mean deg ~5)
        int key = ebuf[i];
        int j = i - 1;
        while (j >= start && ebuf[j] > key) { ebuf[j + 1] = ebuf[j]; j--; }
        ebuf[j + 1] = key;
    }
}

// ---------------- gather aggregation ----------------
// R17 structure (branch-free 8-deep batch; pads load zero row h[N_NODES],
// added unconditionally). R23: bucket layout (start = n*BCAP). Order fixed
// (self, then ascending-e slots incl. zero pads) -> bit-exact across runs.

__global__ __launch_bounds__(256) void gather_agg(const __hip_bfloat16* __restrict__ h,
                                                  const int* __restrict__ deg,
                                                  const int* __restrict__ ebuf,
                                                  __hip_bfloat16* __restrict__ agg) {
    int wave = threadIdx.x >> 6, lane = threadIdx.x & 63;
    int half = lane >> 5, l32 = lane & 31;
    int n = blockIdx.x * 8 + wave * 2 + half;       // 8 nodes per 256-thr block
    bool active = (n < N_NODES);
    int nn = active ? n : 0;
    int dg = active ? deg[nn] : 0;
    int dgc = dg > BCAP ? BCAP : dg;
    int start = nn * BCAP;
    int end = start + dgc;

    float acc[8];
    {
        float sv[8];
        load8(&h[(long long)nn * HID + l32 * 8], sv);   // self row
        #pragma unroll
        for (int k = 0; k < 8; k++) acc[k] = sv[k];
    }

    for (int e = start; e < end; e += 8) {
        int cnt = end - e;                              // >= 1 inside loop
        uint4 raw[8];
        #pragma unroll
        for (int i = 0; i < 8; i++) {
            int t = e + i; t = (t < end) ? t : (end - 1);   // in-bounds ebuf idx
            int idx = ebuf[t];
            int s = (i < cnt) ? idx : N_NODES;              // pad -> zero row
            raw[i] = *(const uint4*)&h[(long long)s * HID + l32 * 8];
        }
        #pragma unroll
        for (int i = 0; i < 8; i++) acc8(raw[i], acc);      // pads add +0.0
    }

    float inv = 1.0f / (float)(dg + 1);
    #pragma unroll
    for (int k = 0; k < 8; k++) acc[k] *= inv;
    if (active) store8(&agg[(long long)n * HID + l32 * 8], acc);
}

// ============ R13/R22: K-concat LDS-staged GEMM, 128-col wide tile ============
// C = [A1|A2] @ [B1|B2]^T as ONE K=512 GEMM. Block = 128 rows x 128 cols
// (cg in {0,1}), 4 waves x (32x128) -> acc[4]; 16 MFMA per barrier.
// Grid (GX=256, 2): 512 blocks = 2/CU; cg duplicates 256 apart -> same XCD L2
// (R19/R20-verified). A XOR-swizzled via pre-swizzled global source; B from
// packed image; 2-phase __syncthreads pipeline (counted-vmcnt regressed, R21).
// MFMA order per acc: t ascending, k16 ascending -> bit-exact.

template <int KS, bool DUAL, typename TC, bool RELU>
__global__ __launch_bounds__(256, 2) void gemm_kc(const __hip_bfloat16* __restrict__ A1,
                                                  const __hip_bfloat16* __restrict__ A2,
                                                  const __hip_bfloat16* __restrict__ Bp1,
                                                  const __hip_bfloat16* __restrict__ Bp2,
                                                  const float* __restrict__ bias,
                                                  TC* __restrict__ C, int M, int GX) {
    const int N = 256;
    const int NSTEP = (DUAL ? 2 : 1) * KS / 64;       // 64-wide K steps
    __shared__ __align__(16) short As[2][128 * 64];   // 2 x 16 KB
    __shared__ __align__(16) short Bs[2][64 * 128];   // 2 x 16 KB  (64 KB total)

    const int tid = threadIdx.x;
    const int w = tid >> 6, lane = tid & 63;
    const int half = lane >> 5, l32 = lane & 31;
    const int cg = blockIdx.y;                        // 0..1 (128-col groups)

    const short* A1s = (const short*)A1;
    const short* A2s = (const short*)A2;
    const short* B1s = (const short*)Bp1;
    const short* B2s = (const short*)Bp2;

    const int NT = (M + 127) / 128;
    for (int tile = blockIdx.x; tile < NT; tile += GX) {
        const int row0 = tile * 128;

        // stage K-step t: A 4 gloads/thread, B 4 gloads/thread
        auto stage = [&](int buf, int t) {
            const short* Asrc; const short* Bsrc; int kl;
            if (!DUAL || t < KS / 64) { Asrc = A1s; Bsrc = B1s; kl = t * 64; }
            else                      { Asrc = A2s; Bsrc = B2s; kl = t * 64 - KS; }
            #pragma unroll
            for (int i = 0; i < 4; i++) {
                int idx = i * 256 + tid;             // 0..1023
                int row = idx >> 3, b16 = idx & 7;
                int gr = row0 + row; if (gr >= M) gr = M - 1;
                gload_lds16(Asrc + (size_t)gr * KS + kl + ((b16 ^ (row & 7)) * 8),
                            (short*)&As[buf][idx * 8]);
            }
            #pragma unroll
            for (int i = 0; i < 4; i++) {
                int idx = i * 256 + tid;             // 0..1023
                int kseg = idx >> 7, col = idx & 127;
                gload_lds16(Bsrc + ((size_t)((kl >> 3) + kseg) * 256 + cg * 128 + col) * 8,
                            (short*)&Bs[buf][idx * 8]);
            }
        };

        floatx16 acc[4] = {};
        int cur = 0;
        stage(0, 0);
        __syncthreads();

        for (int t = 0; t < NSTEP; t++) {
            if (t + 1 < NSTEP) stage(cur ^ 1, t + 1);   // async, overlaps compute

            const int arow = w * 32 + l32;
            #pragma unroll
            for (int k16 = 0; k16 < 4; k16++) {
                int e = k16 * 2 + half;
                short8 a = *(const short8*)&As[cur][(arow * 8 + (e ^ (l32 & 7))) * 8];
                #pragma unroll
                for (int ct = 0; ct < 4; ct++) {
                    short8 b = *(const short8*)&Bs[cur][(e * 128 + ct * 32 + l32) * 8];
                    acc[ct] = __builtin_amdgcn_mfma_f32_32x32x16_bf16(a, b, acc[ct], 0, 0, 0);
                }
            }
            __syncthreads();                            // vmcnt(0)+lgkm+barrier
            cur ^= 1;
        }

        // epilogue: C/D col = lane&31, row = (reg&3) + 8*(reg>>2) + 4*half
        #pragma unroll
        for (int ct = 0; ct < 4; ct++) {
            int c = cg * 128 + ct * 32 + l32;
            float bc = bias[c];
            #pragma unroll
            for (int reg = 0; reg < 16; reg++) {
                int rr = row0 + w * 32 + (reg & 3) + 8 * (reg >> 2) + 4 * half;
                if (rr < M) {
                    float v = acc[ct][reg] + bc;
                    if (RELU) v = fmaxf(v, 0.0f);
                    stf(&C[(size_t)rr * N + c], v);
                }
            }
        }
    }
}

// ---------------- prediction head (R23: build_comb fused into GEMM) ----------------
// A row r of the pred GEMM is comb[r] = [s | d | s*d | |s-d|], s=h[src[r]],
// d=h[dst[r]] — computed on the fly. seg = ka>>8 is wave-uniform (ka spread
// within a wave is < 256-aligned window) -> no divergence. Products use the
// same fp32-mul -> bf16 rounding build_comb used -> bit-identical A values.

__device__ __forceinline__ short8 comb_frag(const __hip_bfloat16* __restrict__ h,
                                            int srow, int drow, int ka) {
    int seg = ka >> 8, off = ka & 255;
    const __hip_bfloat16* ps = &h[(size_t)srow * HID + off];
    const __hip_bfloat16* pd = &h[(size_t)drow * HID + off];
    if (seg == 0) return *(const short8*)ps;
    if (seg == 1) return *(const short8*)pd;
    float s[8], d[8];
    load8(ps, s);
    load8(pd, d);
    __hip_bfloat16 b[8];
    if (seg == 2) {
        #pragma unroll
        for (int j = 0; j < 8; j++) b[j] = __float2bfloat16(s[j] * d[j]);
    } else {
        #pragma unroll
        for (int j = 0; j < 8; j++) b[j] = __float2bfloat16(fabsf(s[j] - d[j]));
    }
    return *(const short8*)b;
}

// rolling-stage MFMA GEMM (K=1024, 16x16x32), single-source, comb-on-the-fly
template <int RT>
__global__ __launch_bounds__(256, 2) void pred_gemm(const __hip_bfloat16* __restrict__ h,
                                                    const int* __restrict__ src_idx,
                                                    const int* __restrict__ dst_idx,
                                                    const __hip_bfloat16* __restrict__ B1,
                                                    const float* __restrict__ bias,
                                                    float* __restrict__ C, int M, int K) {
    const int N = 256;
    const int SZ = 4 * 256 * 8;
    __shared__ __align__(16) short Bs[2][SZ];

    int w = threadIdx.x >> 6, lane = threadIdx.x & 63;
    int quad = lane >> 4, l16 = lane & 15;
    int wr = w >> 1, wc = w & 1;
    const int WROWS = RT * 16;
    int row0 = blockIdx.x * (2 * WROWS) + wr * WROWS;
    int colbase = wc * 128;

    const short* B1s = (const short*)B1;

    floatx4 acc[RT][8] = {};

    int r[RT], sidx[RT], didx[RT];
    #pragma unroll
    for (int i = 0; i < RT; i++) {
        int rr = row0 + i * 16 + l16;
        r[i] = rr < M ? rr : M - 1;
        sidx[i] = clampi(src_idx[r[i]], N_NODES);
        didx[i] = clampi(dst_idx[r[i]], N_NODES);
    }
    int scol = threadIdx.x;
    int ldsoff = (w * 64) * 8;

    short8 a1c[RT], a1n[RT];

    #pragma unroll
    for (int q = 0; q < 4; q++)
        gload_lds16(B1s + (size_t)scol * K + q * 8, &Bs[0][q * 256 * 8 + ldsoff]);
    {
        int ka = quad * 8;
        #pragma unroll
        for (int i = 0; i < RT; i++)
            a1c[i] = comb_frag(h, sidx[i], didx[i], ka);
    }
    __syncthreads();

    const int NK = K / 32;
    int cur = 0;
    for (int k = 0; k < NK; k++) {
        if (k + 1 < NK) {
            int k0n = (k + 1) * 32;
            #pragma unroll
            for (int q = 0; q < 4; q++)
                gload_lds16(B1s + (size_t)scol * K + k0n + q * 8,
                            &Bs[cur ^ 1][q * 256 * 8 + ldsoff]);
            int ka = k0n + quad * 8;
            #pragma unroll
            for (int i = 0; i < RT; i++)
                a1n[i] = comb_frag(h, sidx[i], didx[i], ka);
        }

        short8 b1[8];
        #pragma unroll
        for (int ct = 0; ct < 8; ct++) {
            int col = colbase + ct * 16 + l16;
            b1[ct] = *(const short8*)&Bs[cur][(quad * 256 + col) * 8];
        }
        #pragma unroll
        for (int i = 0; i < RT; i++)
            #pragma unroll
            for (int ct = 0; ct < 8; ct++)
                acc[i][ct] = __builtin_amdgcn_mfma_f32_16x16x32_bf16(a1c[i], b1[ct], acc[i][ct], 0, 0, 0);
        __syncthreads();
        cur ^= 1;
        #pragma unroll
        for (int i = 0; i < RT; i++) a1c[i] = a1n[i];
    }

    #pragma unroll
    for (int rt = 0; rt < RT; rt++) {
        #pragma unroll
        for (int ct = 0; ct < 8; ct++) {
            int c = colbase + ct * 16 + l16;
            float bc = bias[c];
            #pragma unroll
            for (int i = 0; i < 4; i++) {
                int rr = row0 + rt * 16 + quad * 4 + i;
                if (rr < M) {
                    float v = acc[rt][ct][i] + bc;
                    v = fmaxf(v, 0.0f);
                    C[(size_t)rr * N + c] = v;
                }
            }
        }
    }
}

__global__ __launch_bounds__(256) void pred_final(const float* __restrict__ hidden,
                                                  const float* __restrict__ wp2,
                                                  const float* __restrict__ bp2,
                                                  float* __restrict__ out) {
    int wave = threadIdx.x >> 6;
    int lane = threadIdx.x & 63;
    int row = blockIdx.x * 4 + wave;
    if (row >= N_LINKS) return;
    const float4 hv = *(const float4*)&hidden[(long long)row * HID + lane * 4];
    const float4 wv = *(const float4*)&wp2[lane * 4];
    float v = hv.x * wv.x + hv.y * wv.y + hv.z * wv.z + hv.w * wv.w;
    #pragma unroll
    for (int off = 32; off > 0; off >>= 1) v += __shfl_down(v, off, 64);
    if (lane == 0) out[row] = 1.0f / (1.0f + expf(-(v + bp2[0])));
}

// ---------------- launch ----------------

extern "C" void kernel_launch(void* const* d_in, const int* in_sizes, int n_in,
                              void* d_out, int out_size, void* d_ws, size_t ws_size,
                              hipStream_t stream) {
    const float* x          = (const float*)d_in[0];
    const int*   edge_index = (const int*)d_in[1];
    const int*   e_src      = edge_index;            // row 0
    const int*   e_dst      = edge_index + N_EDGES;  // row 1
    const int*   src_idx    = (const int*)d_in[3];
    const int*   dst_idx    = (const int*)d_in[4];
    const float* w_emb      = (const float*)d_in[5];
    const float* b_emb      = (const float*)d_in[6];
    const float* wl0        = (const float*)d_in[8];
    const float* bl0        = (const float*)d_in[9];
    const float* wr0        = (const float*)d_in[10];
    const float* wl1        = (const float*)d_in[13];
    const float* bl1        = (const float*)d_in[14];
    const float* wr1        = (const float*)d_in[15];
    const float* wp1        = (const float*)d_in[18];
    const float* bp1        = (const float*)d_in[19];
    const float* wp2        = (const float*)d_in[20];
    const float* bp2        = (const float*)d_in[21];
    float* out = (float*)d_out;

    typedef __hip_bfloat16 bf16;
    const size_t NH  = (size_t)N_NODES * HID;
    const size_t NH1 = (size_t)(N_NODES + 1) * HID;   // +1 zero row (gather pads)

    // workspace plan (~194 MB; ws proven >= 205 MB)
    char* p = (char*)d_ws;
    bf16* h0   = (bf16*)p;  p += NH1 * 2;                      // 51.2 MB (+512B)
    bf16* h1   = (bf16*)p;  p += NH1 * 2;                      // 51.2 MB (+512B)
    bf16* agg  = (bf16*)p;  p += NH * 2;                       // 51.2 MB
    bf16* xb   = (bf16*)p;  p += (size_t)N_NODES * FEAT * 2;   // 25.6 MB
    bf16* wbp  = (bf16*)p;  p += (size_t)WP_TOTAL * 2;         // 0.6 MB (packed)
    bf16* wbp1 = (bf16*)p;  p += (size_t)WP1_N * 2;            // 0.5 MB (wp1)
    p = (char*)(((uintptr_t)p + 255) & ~(uintptr_t)255);
    int* deg  = (int*)p; p += (size_t)N_NODES * 4;             // 0.4 MB
    int* ebuf = (int*)p; p += (size_t)N_NODES * BCAP * 4;      // 12.8 MB
    const size_t need = (size_t)(p - (char*)d_ws);

    if (ws_size < need) {   // visible failure, no fault
        zero_f32<<<(out_size + 255) / 256, 256, 0, stream>>>(out, out_size);
        return;
    }

    // alias (region dead by the time it's reused):
    float* hidden = (float*)h1;  // [16384][256] fp32 = 16.8 MB <= 51.2

    // ---- init + bucketed adjacency (R23: 3 kernels, was 7) ----
    init_misc<<<(N_NODES + 255) / 256, 256, 0, stream>>>(
        deg, (int*)(h0 + NH), (int*)(h1 + NH));
    fill_buckets<<<(N_EDGES + 255) / 256, 256, 0, stream>>>(e_src, e_dst, deg, ebuf, N_EDGES);
    sort_rows<<<(N_NODES + 255) / 256, 256, 0, stream>>>(deg, ebuf);

    // ---- bf16 conversions (one kernel) ----
    cvt_x<<<((N_NODES * FEAT / 4) + 255) / 256, 256, 0, stream>>>((const float4*)x, xb, N_NODES * FEAT / 4);
    cvt_wall<<<((WP_TOTAL + WP1_N) + 255) / 256, 256, 0, stream>>>(
        w_emb, wl0, wr0, wl1, wr1, wp1, wbp, wbp1);

    const int GX = 256;                     // 256 walkers x 2 cg = 512 blocks, 2/CU
    dim3 pgrid(GX, 2);                      // cg slow; duplicates 256 apart ->
                                            // same XCD L2 (256 % 8 == 0)

    // ---- embedding: h0 = xb @ w_emb^T + b_emb  (KS=128) ----
    gemm_kc<128, false, bf16, false><<<pgrid, 256, 0, stream>>>(
        xb, nullptr, wbp + POF_EMB, nullptr, b_emb, h0, N_NODES, GX);

    // ---- layer 0: h1 = relu(agg@wl0^T + bl0 + h0@wr0^T)  (K-concat 512) ----
    gather_agg<<<(N_NODES + 7) / 8, 256, 0, stream>>>(h0, deg, ebuf, agg);
    gemm_kc<256, true, bf16, true><<<pgrid, 256, 0, stream>>>(
        agg, h0, wbp + POF_L0, wbp + POF_R0, bl0, h1, N_NODES, GX);

    // ---- layer 1: h0 = relu(agg@wl1^T + bl1 + h1@wr1^T) ----
    gather_agg<<<(N_NODES + 7) / 8, 256, 0, stream>>>(h1, deg, ebuf, agg);
    gemm_kc<256, true, bf16, true><<<pgrid, 256, 0, stream>>>(
        agg, h1, wbp + POF_L1, wbp + POF_R1, bl1, h0, N_NODES, GX);

    // ---- prediction head (comb fused into the GEMM) ----
    pred_gemm<2><<<(N_LINKS + 63) / 64, 256, 0, stream>>>(
        h0, src_idx, dst_idx, wbp1, bp1, hidden, N_LINKS, 4 * HID);
    pred_final<<<N_LINKS / 4, 256, 0, stream>>>(hidden, wp2, bp2, out);
}